// Round 1
// 297.366 us; speedup vs baseline: 2.7549x; 2.7549x over previous
//
#include <hip/hip_runtime.h>
#include <math.h>

#define R2 2500.0f
#define EPSF 1e-8f

constexpr int H  = 256;   // feature dim (fixed by problem)
constexpr int HH = 128;   // hidden dim

// ---------------- K1: degree count ----------------
__global__ void k_degree(const int* __restrict__ row, int* __restrict__ deg, int E) {
    int e = blockIdx.x * blockDim.x + threadIdx.x;
    if (e < E) atomicAdd(&deg[row[e]], 1);
}

// ---------------- K2: exclusive scan (single block, 1024 thr) ----------------
__global__ void k_scan(const int* __restrict__ deg, int* __restrict__ row_ptr, int N) {
    __shared__ int s[1024];
    int t = threadIdx.x;
    int per = N >> 10;            // N/1024 (N=16384 -> 16)
    int base = t * per;
    int vals[32];
    int local = 0;
    for (int k = 0; k < per; k++) { vals[k] = deg[base + k]; local += vals[k]; }
    s[t] = local;
    __syncthreads();
    for (int off = 1; off < 1024; off <<= 1) {
        int v = s[t];
        int add = (t >= off) ? s[t - off] : 0;
        __syncthreads();
        s[t] = v + add;
        __syncthreads();
    }
    int excl = (t > 0) ? s[t - 1] : 0;
    for (int k = 0; k < per; k++) { row_ptr[base + k] = excl; excl += vals[k]; }
    if (t == 1023) row_ptr[N] = excl;
}

// ---------------- K3: CSR fill ----------------
__global__ void k_fill(const int* __restrict__ row, const int* __restrict__ col,
                       const int* __restrict__ row_ptr, int* __restrict__ fill,
                       int* __restrict__ cols, int E) {
    int e = blockIdx.x * blockDim.x + threadIdx.x;
    if (e < E) {
        int r = row[e];
        int p = row_ptr[r] + atomicAdd(&fill[r], 1);
        cols[p] = col[e];
    }
}

// ---------------- K4: spatial density (pairwise count) ----------------
__global__ void k_density(const float* __restrict__ coords, int* __restrict__ dens,
                          int N, int jPer) {
    __shared__ float sx[256], sy[256], sq[256];
    int i = blockIdx.x * 256 + threadIdx.x;
    const float2* c2 = (const float2*)coords;
    float2 ci = c2[i];
    float sqi = ci.x * ci.x + ci.y * ci.y;
    int j0 = blockIdx.y * jPer;
    int cnt = 0;
    for (int jt = j0; jt < j0 + jPer; jt += 256) {
        float2 cj = c2[jt + threadIdx.x];
        sx[threadIdx.x] = cj.x;
        sy[threadIdx.x] = cj.y;
        sq[threadIdx.x] = cj.x * cj.x + cj.y * cj.y;
        __syncthreads();
#pragma unroll 8
        for (int k = 0; k < 256; k++) {
            float dot = ci.x * sx[k] + ci.y * sy[k];
            float d2 = (sqi + sq[k]) - 2.0f * dot;
            cnt += (d2 <= R2) ? 1 : 0;
        }
        __syncthreads();
    }
    atomicAdd(&dens[i], cnt);
}

// ---------------- K5: fvar via CSR gather, async direct-to-LDS ----------------
// One wave per node. Per batch: 8 independent global_load_lds (1KB row each,
// zero VGPR cost -> guaranteed 8 outstanding per wave), one waitcnt, then
// ds_read_b128 + accumulate. Indices preloaded 64-at-a-time + __shfl broadcast
// so the index load is off the critical chain.
// NOTE: no global atomics here anymore — the 3x16384 same-cacheline atomicMax
// epilogue was the dominant cost of the whole pipeline (~500us of same-line
// RMW serialization at one TCC). Maxima now computed in k_scal.
__global__ void __launch_bounds__(256) k_fvar(
    const float* __restrict__ x, const int* __restrict__ row_ptr,
    const int* __restrict__ cols, float* __restrict__ fvar, int N) {
    __shared__ float4 lds[4][8][64];   // 4 waves x 8 slots x 1KB = 32KB
    int wave = threadIdx.x >> 6;
    int lane = threadIdx.x & 63;
    int i = blockIdx.x * 4 + wave;     // grid = N/4 exact
    int s = row_ptr[i], e = row_ptr[i + 1];
    const float4* xb = (const float4*)x;   // 64 float4 per row
    float4 acc = make_float4(0.f, 0.f, 0.f, 0.f);
    for (int p0 = s; p0 < e; p0 += 64) {
        int m = e - p0; if (m > 64) m = 64;
        int idx = cols[p0 + (lane < m ? lane : m - 1)];
        for (int j = 0; j < m; j += 8) {
            int nb = m - j; if (nb > 8) nb = 8;
#pragma unroll
            for (int k = 0; k < 8; k++) {
                if (k < nb) {
                    int c = __shfl(idx, j + k, 64);
                    const float4* gp = xb + (size_t)c * 64 + lane;
                    __builtin_amdgcn_global_load_lds(
                        (const __attribute__((address_space(1))) void*)gp,
                        (__attribute__((address_space(3))) void*)(&lds[wave][k][0]),
                        16, 0, 0);
                }
            }
            __builtin_amdgcn_s_waitcnt(0);   // drain the 8 async row fetches
#pragma unroll
            for (int k = 0; k < 8; k++) {
                if (k < nb) {
                    float4 v = lds[wave][k][lane];
                    acc.x += v.x; acc.y += v.y; acc.z += v.z; acc.w += v.w;
                }
            }
        }
    }
    float cnt = fmaxf((float)(e - s), 1.0f);
    float4 xi = xb[(size_t)i * 64 + lane];
    float dx = xi.x - acc.x / cnt;
    float dy = xi.y - acc.y / cnt;
    float dz = xi.z - acc.z / cnt;
    float dw = xi.w - acc.w / cnt;
    float ss = dx * dx + dy * dy + dz * dz + dw * dw;
#pragma unroll
    for (int off = 32; off > 0; off >>= 1) ss += __shfl_xor(ss, off, 64);
    if (lane == 0) fvar[i] = sqrtf(ss);
}

// ---------------- K5b: maxima reduction (deg, dens, fvar) ----------------
// 64 blocks x 256 thr, grid-stride over N, shfl+LDS reduce, one atomicMax
// per quantity per block (192 total atomics -> no contention).
__global__ void __launch_bounds__(256) k_scal(
    const int* __restrict__ deg, const int* __restrict__ dens,
    const float* __restrict__ fvar, int* __restrict__ scal, int N) {
    __shared__ int sd[4], sn[4];
    __shared__ float sf[4];
    int t = threadIdx.x;
    int g = blockIdx.x * 256 + t;
    int stride = 256 * gridDim.x;
    int md = 0, mn = 0;
    float mf = 0.f;
    for (int i = g; i < N; i += stride) {
        md = max(md, deg[i]);
        mn = max(mn, dens[i]);
        mf = fmaxf(mf, fvar[i]);
    }
#pragma unroll
    for (int off = 32; off > 0; off >>= 1) {
        md = max(md, __shfl_xor(md, off, 64));
        mn = max(mn, __shfl_xor(mn, off, 64));
        mf = fmaxf(mf, __shfl_xor(mf, off, 64));
    }
    int w = t >> 6, l = t & 63;
    if (l == 0) { sd[w] = md; sn[w] = mn; sf[w] = mf; }
    __syncthreads();
    if (t == 0) {
#pragma unroll
        for (int k = 1; k < 4; k++) {
            md = max(md, sd[k]);
            mn = max(mn, sn[k]);
            mf = fmaxf(mf, sf[k]);
        }
        atomicMax(&scal[0], md);
        atomicMax(&scal[1], mn);
        atomicMax(&scal[2], __float_as_int(mf));   // nonneg float: int-max ok
    }
}

// ---------------- K6: tiny MLP ----------------
__global__ void __launch_bounds__(256) k_mlp(
    const float* __restrict__ w1, const float* __restrict__ b1,
    const float* __restrict__ w2, const float* __restrict__ b2,
    const int* __restrict__ deg, const int* __restrict__ dens,
    const float* __restrict__ fvar, const int* __restrict__ scal,
    float* __restrict__ out, int N) {
    __shared__ float sh_h[HH];
    int j = threadIdx.x;
    float wv[HH];
#pragma unroll
    for (int l = 0; l < HH; l++) wv[l] = w2[l * H + j];
    float bj = b2[j];
    float maxdeg  = (float)scal[0] + EPSF;
    float maxdens = (float)(scal[1] - 1) + EPSF;
    float maxfv   = __int_as_float(scal[2]) + EPSF;
    float w1a = 0.f, w1b = 0.f, w1c = 0.f, b1j = 0.f;
    if (j < HH) { w1a = w1[j]; w1b = w1[HH + j]; w1c = w1[2 * HH + j]; b1j = b1[j]; }
    for (int i = blockIdx.x; i < N; i += gridDim.x) {
        float f0 = (float)deg[i] / maxdeg;
        float f1 = (float)(dens[i] - 1) / maxdens;
        float f2 = fvar[i] / maxfv;
        if (j < HH) {
            float h = f0 * w1a + f1 * w1b + f2 * w1c + b1j;
            sh_h[j] = fmaxf(h, 0.0f);
        }
        __syncthreads();
        float acc = bj;
#pragma unroll
        for (int l = 0; l < HH; l++) acc = fmaf(sh_h[l], wv[l], acc);
        out[(size_t)i * H + j] = acc;
        __syncthreads();
    }
}

extern "C" void kernel_launch(void* const* d_in, const int* in_sizes, int n_in,
                              void* d_out, int out_size, void* d_ws, size_t ws_size,
                              hipStream_t stream) {
    const float* x      = (const float*)d_in[0];
    const int*   ei     = (const int*)d_in[1];
    const float* coords = (const float*)d_in[2];
    const float* w1     = (const float*)d_in[3];
    const float* b1     = (const float*)d_in[4];
    const float* w2     = (const float*)d_in[5];
    const float* b2     = (const float*)d_in[6];
    float* out = (float*)d_out;

    const int N = in_sizes[2] / 2;   // 16384
    const int E = in_sizes[1] / 2;   // 524288
    const int* row = ei;
    const int* col = ei + E;

    // workspace layout (int32 elements)
    int* ws       = (int*)d_ws;
    int* deg_cnt  = ws;                    // [N]   zeroed
    int* dens_cnt = ws + N;                // [N]   zeroed
    int* fill     = ws + 2 * N;            // [N]   zeroed
    int* scal     = ws + 3 * N;            // [4]   zeroed
    float* fvarp  = (float*)(ws + 3 * N + 4); // [N]
    int* row_ptr  = ws + 4 * N + 4;        // [N+1]
    int* cols     = ws + 5 * N + 5;        // [E]

    hipMemsetAsync(ws, 0, (size_t)(3 * N + 4) * sizeof(int), stream);

    int eb = (E + 255) / 256;
    k_degree<<<eb, 256, 0, stream>>>(row, deg_cnt, E);
    k_scan<<<1, 1024, 0, stream>>>(deg_cnt, row_ptr, N);
    k_fill<<<eb, 256, 0, stream>>>(row, col, row_ptr, fill, cols, E);

    const int NSLICE = 8;
    k_density<<<dim3(N / 256, NSLICE), 256, 0, stream>>>(coords, dens_cnt, N, N / NSLICE);

    k_fvar<<<N / 4, 256, 0, stream>>>(x, row_ptr, cols, fvarp, N);

    k_scal<<<64, 256, 0, stream>>>(deg_cnt, dens_cnt, fvarp, scal, N);

    k_mlp<<<1024, 256, 0, stream>>>(w1, b1, w2, b2, deg_cnt, dens_cnt, fvarp, scal,
                                    out, N);
}